// Round 1
// baseline (587.620 us; speedup 1.0000x reference)
//
#include <hip/hip_runtime.h>
#include <hip/hip_bf16.h>

// Problem constants
#define BB 4
#define TT 2048
#define DIM 512
#define NH 8
#define DH 64
#define DECAY 0.9f

// Retention chunking
#define CC 64     // retention chunk length
#define NC 32     // TT / CC
#define BHN 32    // BB * NH

// Scan chunking
#define CHS 128   // scan chunk length
#define NSC 16    // TT / CHS

// ---------------------------------------------------------------------------
// Fused GEMM: C[r, c] = act( (A .* A2?)[r,:] @ W[:,c] + bias[c] )
// M=8192, N=K=512. 64x64 tile, 256 threads, 4x4 microtile, K-tile 16.
// ---------------------------------------------------------------------------
__global__ __launch_bounds__(256) void gemm_act(
    const float* __restrict__ A, const float* __restrict__ A2,
    const float* __restrict__ W, const float* __restrict__ bias,
    float* __restrict__ C, int act) {
  __shared__ float As[16][68];  // [k2][row], pad 68 -> conflict-free + 16B aligned
  __shared__ float Bs[16][64];  // [k2][col]
  int tid = threadIdx.x;
  int rowTile = blockIdx.y * 64;
  int colTile = blockIdx.x * 64;
  int tx = tid & 15, ty = tid >> 4;
  float acc[4][4] = {};
  for (int kk = 0; kk < DIM; kk += 16) {
#pragma unroll
    for (int l = 0; l < 4; ++l) {
      int e = tid + 256 * l;
      int r = e >> 4, k2 = e & 15;
      size_t ga = (size_t)(rowTile + r) * DIM + kk + k2;
      float vA = A[ga];
      if (A2) vA *= A2[ga];
      As[k2][r] = vA;
      int j = e & 63, k2b = e >> 6;
      Bs[k2b][j] = W[(size_t)(kk + k2b) * DIM + colTile + j];
    }
    __syncthreads();
#pragma unroll
    for (int k2 = 0; k2 < 16; ++k2) {
      float4 av = *(const float4*)&As[k2][ty * 4];
      float4 bv = *(const float4*)&Bs[k2][tx * 4];
      float ar[4] = {av.x, av.y, av.z, av.w};
      float br[4] = {bv.x, bv.y, bv.z, bv.w};
#pragma unroll
      for (int i2 = 0; i2 < 4; ++i2)
#pragma unroll
        for (int j2 = 0; j2 < 4; ++j2)
          acc[i2][j2] = fmaf(ar[i2], br[j2], acc[i2][j2]);
    }
    __syncthreads();
  }
#pragma unroll
  for (int i2 = 0; i2 < 4; ++i2) {
    int r = rowTile + ty * 4 + i2;
#pragma unroll
    for (int j2 = 0; j2 < 4; ++j2) {
      int col = colTile + tx * 4 + j2;
      float vC = acc[i2][j2] + bias[col];
      if (act == 1) vC = 1.0f / (1.0f + __expf(-vC));
      C[(size_t)r * DIM + col] = vC;
    }
  }
}

// ---------------------------------------------------------------------------
// 3-phase chunk-parallel linear scan: h_t = a_t * h_{t-1} + b_t  (axis t)
// channels = B*DIM = 2048, chunks of CHS=128
// ---------------------------------------------------------------------------
__global__ void scan_part(const float* __restrict__ a, const float* __restrict__ b,
                          float* __restrict__ SA, float* __restrict__ SB) {
  int ci = blockIdx.x;
  int ch = blockIdx.y * 256 + threadIdx.x;  // [0, 2048)
  int bb = ch >> 9, d = ch & 511;
  size_t base = ((size_t)bb * TT + ci * CHS) * DIM + d;
  float h = 0.f, pA = 1.f;
  for (int t = 0; t < CHS; ++t) {
    float av = a[base + (size_t)t * DIM];
    float bv = b[base + (size_t)t * DIM];
    h = fmaf(av, h, bv);
    pA *= av;
  }
  SA[ci * 2048 + ch] = pA;
  SB[ci * 2048 + ch] = h;
}

__global__ void scan_carry(const float* __restrict__ SA, const float* __restrict__ SB,
                           float* __restrict__ CY) {
  int ch = blockIdx.x * 256 + threadIdx.x;  // [0, 2048)
  float carry = 0.f;
  for (int ci = 0; ci < NSC; ++ci) {
    CY[ci * 2048 + ch] = carry;
    carry = fmaf(SA[ci * 2048 + ch], carry, SB[ci * 2048 + ch]);
  }
}

__global__ void scan_apply(const float* __restrict__ a, float* __restrict__ hb,
                           const float* __restrict__ CY) {
  int ci = blockIdx.x;
  int ch = blockIdx.y * 256 + threadIdx.x;
  int bb = ch >> 9, d = ch & 511;
  size_t base = ((size_t)bb * TT + ci * CHS) * DIM + d;
  float h = CY[ci * 2048 + ch];
  for (int t = 0; t < CHS; ++t) {
    float av = a[base + (size_t)t * DIM];
    float bv = hb[base + (size_t)t * DIM];
    h = fmaf(av, h, bv);
    hb[base + (size_t)t * DIM] = h;  // in-place: b -> h
  }
}

// ---------------------------------------------------------------------------
// Retention phase 1: per-chunk KV summary
// KV[c][bh][d][e] = sum_j decay^{CC-1-j} k[b, cC+j, h*DH+d] * v[b, cC+j, h*DH+e]
// ---------------------------------------------------------------------------
__global__ __launch_bounds__(256) void ret_kv(const float* __restrict__ k,
                                              const float* __restrict__ v,
                                              float* __restrict__ KV) {
  int bh = blockIdx.x, c = blockIdx.y;
  int b = bh >> 3, h = bh & 7;
  __shared__ float kt[CC][DH + 1];
  __shared__ float vt[CC][DH + 1];
  __shared__ float dp[CC];
  int tid = threadIdx.x;
  size_t base = ((size_t)(b * TT + c * CC)) * DIM + h * DH;
#pragma unroll
  for (int l = 0; l < 16; ++l) {
    int e = tid + 256 * l;  // [0, 4096)
    int j = e >> 6, d = e & 63;
    kt[j][d] = k[base + (size_t)j * DIM + d];
    vt[j][d] = v[base + (size_t)j * DIM + d];
  }
  if (tid < CC) dp[tid] = __powf(DECAY, (float)(CC - 1 - tid));
  __syncthreads();
  int d = tid >> 2, e0 = (tid & 3) * 16;
  float acc[16];
#pragma unroll
  for (int u = 0; u < 16; ++u) acc[u] = 0.f;
  for (int j = 0; j < CC; ++j) {
    float kd = kt[j][d] * dp[j];
#pragma unroll
    for (int u = 0; u < 16; ++u) acc[u] = fmaf(kd, vt[j][e0 + u], acc[u]);
  }
  float* o = KV + ((size_t)(c * BHN + bh)) * 4096 + d * 64 + e0;
#pragma unroll
  for (int u = 0; u < 16; ++u) o[u] = acc[u];
}

// ---------------------------------------------------------------------------
// Retention phase 2: exclusive scan over chunks (in place):
// P_c = decay^CC * P_{c-1} + KV_{c-1};  KV[c] is replaced by P_c
// ---------------------------------------------------------------------------
__global__ void ret_scan(float* __restrict__ KV) {
  int gid = blockIdx.x * 256 + threadIdx.x;  // [0, 131072)
  int bh = gid >> 12, de = gid & 4095;
  float carry = 0.f;
  const float dC = __powf(DECAY, (float)CC);
  for (int c = 0; c < NC; ++c) {
    size_t idx = ((size_t)(c * BHN + bh)) * 4096 + de;
    float kv = KV[idx];
    KV[idx] = carry;
    carry = fmaf(dC, carry, kv);
  }
}

// ---------------------------------------------------------------------------
// Retention phase 3: per-chunk output (added onto m_out already in `out`):
// out[i][e] += sum_{j<=i} decay^{i-j} (q_i . k_j) v_j[e] + decay^{i+1} (q_i @ P_c)[e]
// ---------------------------------------------------------------------------
__global__ __launch_bounds__(256) void ret_out(const float* __restrict__ q,
                                               const float* __restrict__ k,
                                               const float* __restrict__ v,
                                               const float* __restrict__ P,
                                               float* __restrict__ out) {
  int bh = blockIdx.x, c = blockIdx.y;
  int b = bh >> 3, h = bh & 7;
  __shared__ float qt[CC][DH + 1];
  __shared__ float kt[CC][DH + 1];  // reused for v after scores
  __shared__ float sc[CC][CC + 2];
  __shared__ float dp[CC + 1];
  int tid = threadIdx.x;
  size_t base = ((size_t)(b * TT + c * CC)) * DIM + h * DH;
#pragma unroll
  for (int l = 0; l < 16; ++l) {
    int e = tid + 256 * l;
    int j = e >> 6, d = e & 63;
    qt[j][d] = q[base + (size_t)j * DIM + d];
    kt[j][d] = k[base + (size_t)j * DIM + d];
  }
  if (tid <= CC) dp[tid] = __powf(DECAY, (float)tid);
  __syncthreads();
  int i = tid >> 2, j0 = (tid & 3) * 16;
  // scores (zero above diagonal so the second GEMM can be a uniform full sum)
  for (int jj = 0; jj < 16; ++jj) {
    int j = j0 + jj;
    float s = 0.f;
    if (j <= i) {
      for (int d = 0; d < DH; ++d) s = fmaf(qt[i][d], kt[j][d], s);
      s *= dp[i - j];
    }
    sc[i][j] = s;
  }
  __syncthreads();
  // overwrite kt with v tile
#pragma unroll
  for (int l = 0; l < 16; ++l) {
    int e = tid + 256 * l;
    int j = e >> 6, d = e & 63;
    kt[j][d] = v[base + (size_t)j * DIM + d];
  }
  // inter-chunk: acc = decay^{i+1} * q_i @ P_c   (P from global, L1/L2-resident)
  int e0 = j0;
  float acc[16];
#pragma unroll
  for (int u = 0; u < 16; ++u) acc[u] = 0.f;
  const float* Pg = P + ((size_t)(c * BHN + bh)) * 4096;
  for (int d = 0; d < DH; ++d) {
    float qd = qt[i][d];
#pragma unroll
    for (int u = 0; u < 16; ++u) acc[u] = fmaf(qd, Pg[d * 64 + e0 + u], acc[u]);
  }
  float di = dp[i + 1];
#pragma unroll
  for (int u = 0; u < 16; ++u) acc[u] *= di;
  __syncthreads();  // v tile ready
  for (int j = 0; j < CC; ++j) {
    float s = sc[i][j];
#pragma unroll
    for (int u = 0; u < 16; ++u) acc[u] = fmaf(s, kt[j][e0 + u], acc[u]);
  }
  float* op = out + base;
#pragma unroll
  for (int u = 0; u < 16; ++u) op[(size_t)i * DIM + e0 + u] += acc[u];
}

// ---------------------------------------------------------------------------
extern "C" void kernel_launch(void* const* d_in, const int* in_sizes, int n_in,
                              void* d_out, int out_size, void* d_ws, size_t ws_size,
                              hipStream_t stream) {
  const float* q  = (const float*)d_in[0];
  const float* k  = (const float*)d_in[1];
  const float* v  = (const float*)d_in[2];
  const float* Wa = (const float*)d_in[3];
  const float* ba = (const float*)d_in[4];
  const float* Wb = (const float*)d_in[5];
  const float* bb = (const float*)d_in[6];
  const float* Wg = (const float*)d_in[7];
  const float* bg = (const float*)d_in[8];
  const float* Wo = (const float*)d_in[9];
  const float* bo = (const float*)d_in[10];
  float* out = (float*)d_out;
  float* ws = (float*)d_ws;

  const size_t NEL = (size_t)BB * TT * DIM;  // 4,194,304
  float* Abuf = ws;            // a = sigmoid(qWa+ba); later reused as KV
  float* Bbuf = ws + NEL;      // b = qWb+bb -> h (in place)
  float* Gbuf = ws + 2 * NEL;  // g = sigmoid(qWg+bg)
  float* SA = ws + 3 * NEL;    // [NSC][2048]
  float* SB = SA + NSC * 2048;
  float* CY = SB + NSC * 2048;
  float* KV = Abuf;            // [NC][BHN][64][64], aliases Abuf after scan done

  dim3 ggrid(DIM / 64, (BB * TT) / 64);  // (8, 128)

  gemm_act<<<ggrid, 256, 0, stream>>>(q, nullptr, Wa, ba, Abuf, 1);
  gemm_act<<<ggrid, 256, 0, stream>>>(q, nullptr, Wb, bb, Bbuf, 0);
  gemm_act<<<ggrid, 256, 0, stream>>>(q, nullptr, Wg, bg, Gbuf, 1);

  scan_part<<<dim3(NSC, 8), 256, 0, stream>>>(Abuf, Bbuf, SA, SB);
  scan_carry<<<8, 256, 0, stream>>>(SA, SB, CY);
  scan_apply<<<dim3(NSC, 8), 256, 0, stream>>>(Abuf, Bbuf, CY);

  // m_out = (h*g) @ Wo + bo  -> written directly to out
  gemm_act<<<ggrid, 256, 0, stream>>>(Bbuf, Gbuf, Wo, bo, out, 0);

  // retention (Abuf free now; KV aliases it)
  ret_kv<<<dim3(BHN, NC), 256, 0, stream>>>(k, v, KV);
  ret_scan<<<(BHN * 4096) / 256, 256, 0, stream>>>(KV);
  ret_out<<<dim3(BHN, NC), 256, 0, stream>>>(q, k, v, KV, out);
}

// Round 2
// 324.519 us; speedup vs baseline: 1.8107x; 1.8107x over previous
//
#include <hip/hip_runtime.h>
#include <hip/hip_bf16.h>

typedef unsigned short u16;

// Problem constants
#define BB 4
#define TT 2048
#define DIM 512
#define NH 8
#define DH 64
#define DECAY 0.9f

// Retention chunking
#define CC 64
#define NC 32
#define BHN 32

// Scan chunking
#define CHS 128
#define NSC 16

// GEMM tiling
#define TM 128
#define TN 128
#define BK 64

typedef __attribute__((ext_vector_type(8))) short bf16x8;
typedef __attribute__((ext_vector_type(4))) float f32x4;

__device__ __forceinline__ u16 f2bfu(float f) {
  union { float f; unsigned int u; } c; c.f = f;
  unsigned int u = c.u + 0x7FFFu + ((c.u >> 16) & 1u);  // RNE
  return (u16)(u >> 16);
}

__device__ __forceinline__ void gl_lds16(const void* g, void* l) {
  __builtin_amdgcn_global_load_lds(
      (const __attribute__((address_space(1))) void*)g,
      (__attribute__((address_space(3))) void*)(unsigned int)(unsigned long long)l,
      16, 0, 0);
}

// ---------------------------------------------------------------------------
// cvt: fp32 -> bf16 (4 elems/thread)
// ---------------------------------------------------------------------------
__global__ void cvt_bf16(const float* __restrict__ x, u16* __restrict__ y) {
  int i = blockIdx.x * 256 + threadIdx.x;
  float4 f = ((const float4*)x)[i];
  ushort4 u;
  u.x = f2bfu(f.x); u.y = f2bfu(f.y); u.z = f2bfu(f.z); u.w = f2bfu(f.w);
  ((ushort4*)y)[i] = u;
}

// ---------------------------------------------------------------------------
// weight transpose + convert: Wt[m][n][k] = bf16(W_m[k][n]), m in 0..3
// ---------------------------------------------------------------------------
__global__ void wtrans(const float* __restrict__ W0, const float* __restrict__ W1,
                       const float* __restrict__ W2, const float* __restrict__ W3,
                       u16* __restrict__ Wt) {
  __shared__ float t[32][33];
  int m = blockIdx.z;
  const float* W = (m == 0) ? W0 : (m == 1) ? W1 : (m == 2) ? W2 : W3;
  int n0 = blockIdx.x * 32, k0 = blockIdx.y * 32;
  int tx = threadIdx.x & 31, ty = threadIdx.x >> 5;  // 32 x 8
#pragma unroll
  for (int r = 0; r < 32; r += 8)
    t[ty + r][tx] = W[(size_t)(k0 + ty + r) * DIM + n0 + tx];
  __syncthreads();
  u16* o = Wt + (size_t)m * DIM * DIM;
#pragma unroll
  for (int r = 0; r < 32; r += 8)
    o[(size_t)(n0 + ty + r) * DIM + k0 + tx] = f2bfu(t[tx][ty + r]);
}

// ---------------------------------------------------------------------------
// MFMA GEMM: C[m][n] = act( A[m][:] . Bt[n][:] + bias[n] )
// A: Mx512 bf16, Bt: Ntot x 512 bf16 (pre-transposed weights).
// 128x128 tile, 4 waves, each 64x64 via 4x4 mfma_f32_16x16x32_bf16 frags.
// LDS layout: 16B granules, offset = row*8 + (gk ^ (row&7))  (XOR swizzle:
// staging stays contiguous for global_load_lds, frag reads 2-way max).
// Output cols are grouped per 512: group g -> Cg with optional sigmoid.
// ---------------------------------------------------------------------------
__global__ __launch_bounds__(256) void gemm_bt(
    const u16* __restrict__ A, const u16* __restrict__ Bt,
    const float* __restrict__ b0, const float* __restrict__ b1,
    const float* __restrict__ b2,
    float* __restrict__ C0, float* __restrict__ C1, float* __restrict__ C2,
    int act_mask) {
  __shared__ __align__(16) u16 As[TM * BK];
  __shared__ __align__(16) u16 Bs[TN * BK];
  int tid = threadIdx.x;
  int wave = tid >> 6, lane = tid & 63;
  int nTile = blockIdx.x, mTile = blockIdx.y;
  int group = (nTile * TN) >> 9;
  const float* bias = (group == 0) ? b0 : (group == 1) ? b1 : b2;
  float* C = (group == 0) ? C0 : (group == 1) ? C1 : C2;
  int act = (act_mask >> group) & 1;

  int wm = (wave >> 1) * 64, wn = (wave & 1) * 64;
  int rowA = lane & 15, khalf = lane >> 4;

  f32x4 acc[4][4];
#pragma unroll
  for (int i = 0; i < 4; ++i)
#pragma unroll
    for (int j = 0; j < 4; ++j) acc[i][j] = (f32x4){0.f, 0.f, 0.f, 0.f};

  const u16* Abase = A + (size_t)mTile * TM * 512;
  const u16* Bbase = Bt + (size_t)nTile * TN * 512;

  for (int kk = 0; kk < 512; kk += BK) {
#pragma unroll
    for (int i = 0; i < 4; ++i) {
      int o = (wave * 4 + i) * 64 + lane;
      int row = o >> 3, gk = (o & 7) ^ (row & 7);
      gl_lds16(Abase + (size_t)row * 512 + kk + gk * 8, &As[o * 8]);
    }
#pragma unroll
    for (int i = 0; i < 4; ++i) {
      int o = (wave * 4 + i) * 64 + lane;
      int row = o >> 3, gk = (o & 7) ^ (row & 7);
      gl_lds16(Bbase + (size_t)row * 512 + kk + gk * 8, &Bs[o * 8]);
    }
    __syncthreads();
#pragma unroll
    for (int k0 = 0; k0 < 2; ++k0) {
      bf16x8 af[4], bfr[4];
#pragma unroll
      for (int mi = 0; mi < 4; ++mi) {
        int row = wm + mi * 16 + rowA;
        int gk = k0 * 4 + khalf;
        int o = row * 8 + (gk ^ (row & 7));
        af[mi] = *(const bf16x8*)&As[o * 8];
      }
#pragma unroll
      for (int ni = 0; ni < 4; ++ni) {
        int row = wn + ni * 16 + rowA;
        int gk = k0 * 4 + khalf;
        int o = row * 8 + (gk ^ (row & 7));
        bfr[ni] = *(const bf16x8*)&Bs[o * 8];
      }
#pragma unroll
      for (int mi = 0; mi < 4; ++mi)
#pragma unroll
        for (int ni = 0; ni < 4; ++ni)
          acc[mi][ni] = __builtin_amdgcn_mfma_f32_16x16x32_bf16(
              af[mi], bfr[ni], acc[mi][ni], 0, 0, 0);
    }
    __syncthreads();
  }
  // epilogue: C/D layout col=lane&15, row=(lane>>4)*4+reg  [m89/m91]
  int cloc = lane & 15, rq = (lane >> 4) * 4;
#pragma unroll
  for (int mi = 0; mi < 4; ++mi) {
#pragma unroll
    for (int r = 0; r < 4; ++r) {
      int m = mTile * TM + wm + mi * 16 + rq + r;
#pragma unroll
      for (int ni = 0; ni < 4; ++ni) {
        int n = (nTile * TN + wn + ni * 16 + cloc) & 511;
        float vv = acc[mi][ni][r] + bias[n];
        if (act) vv = 1.0f / (1.0f + __expf(-vv));
        C[(size_t)m * 512 + n] = vv;
      }
    }
  }
}

// ---------------------------------------------------------------------------
// 3-phase chunk-parallel linear scan: h_t = a_t * h_{t-1} + b_t
// ---------------------------------------------------------------------------
__global__ void scan_part(const float* __restrict__ a, const float* __restrict__ b,
                          float* __restrict__ SA, float* __restrict__ SB) {
  int ci = blockIdx.x;
  int ch = blockIdx.y * 256 + threadIdx.x;
  int bb = ch >> 9, d = ch & 511;
  size_t base = ((size_t)bb * TT + ci * CHS) * DIM + d;
  float h = 0.f, pA = 1.f;
  for (int t = 0; t < CHS; ++t) {
    float av = a[base + (size_t)t * DIM];
    float bv = b[base + (size_t)t * DIM];
    h = fmaf(av, h, bv);
    pA *= av;
  }
  SA[ci * 2048 + ch] = pA;
  SB[ci * 2048 + ch] = h;
}

__global__ void scan_carry(const float* __restrict__ SA, const float* __restrict__ SB,
                           float* __restrict__ CY) {
  int ch = blockIdx.x * 256 + threadIdx.x;
  float carry = 0.f;
  for (int ci = 0; ci < NSC; ++ci) {
    CY[ci * 2048 + ch] = carry;
    carry = fmaf(SA[ci * 2048 + ch], carry, SB[ci * 2048 + ch]);
  }
}

// apply + gate + bf16 convert fused: hg = bf16(h * g)
__global__ void scan_apply(const float* __restrict__ a, const float* __restrict__ b,
                           const float* __restrict__ g, const float* __restrict__ CY,
                           u16* __restrict__ hg) {
  int ci = blockIdx.x;
  int ch = blockIdx.y * 256 + threadIdx.x;
  int bb = ch >> 9, d = ch & 511;
  size_t base = ((size_t)bb * TT + ci * CHS) * DIM + d;
  float h = CY[ci * 2048 + ch];
  for (int t = 0; t < CHS; ++t) {
    size_t idx = base + (size_t)t * DIM;
    h = fmaf(a[idx], h, b[idx]);
    hg[idx] = f2bfu(h * g[idx]);
  }
}

// ---------------------------------------------------------------------------
// Retention phase 1: per-chunk KV summary
// ---------------------------------------------------------------------------
__global__ __launch_bounds__(256) void ret_kv(const float* __restrict__ k,
                                              const float* __restrict__ v,
                                              float* __restrict__ KV) {
  int bh = blockIdx.x, c = blockIdx.y;
  int b = bh >> 3, h = bh & 7;
  __shared__ float kt[CC][DH + 1];
  __shared__ float vt[CC][DH + 1];
  __shared__ float dp[CC];
  int tid = threadIdx.x;
  size_t base = ((size_t)(b * TT + c * CC)) * DIM + h * DH;
#pragma unroll
  for (int l = 0; l < 16; ++l) {
    int e = tid + 256 * l;
    int j = e >> 6, d = e & 63;
    kt[j][d] = k[base + (size_t)j * DIM + d];
    vt[j][d] = v[base + (size_t)j * DIM + d];
  }
  if (tid < CC) dp[tid] = __powf(DECAY, (float)(CC - 1 - tid));
  __syncthreads();
  int d = tid >> 2, e0 = (tid & 3) * 16;
  float acc[16];
#pragma unroll
  for (int u = 0; u < 16; ++u) acc[u] = 0.f;
  for (int j = 0; j < CC; ++j) {
    float kd = kt[j][d] * dp[j];
#pragma unroll
    for (int u = 0; u < 16; ++u) acc[u] = fmaf(kd, vt[j][e0 + u], acc[u]);
  }
  float* o = KV + ((size_t)(c * BHN + bh)) * 4096 + d * 64 + e0;
#pragma unroll
  for (int u = 0; u < 16; ++u) o[u] = acc[u];
}

// ---------------------------------------------------------------------------
// Retention phase 2: exclusive chunk scan (in place)
// ---------------------------------------------------------------------------
__global__ void ret_scan(float* __restrict__ KV) {
  int gid = blockIdx.x * 256 + threadIdx.x;
  int bh = gid >> 12, de = gid & 4095;
  float carry = 0.f;
  const float dC = __powf(DECAY, (float)CC);
  for (int c = 0; c < NC; ++c) {
    size_t idx = ((size_t)(c * BHN + bh)) * 4096 + de;
    float kv = KV[idx];
    KV[idx] = carry;
    carry = fmaf(dC, carry, kv);
  }
}

// ---------------------------------------------------------------------------
// Retention phase 3: per-chunk output, added onto m_out
// ---------------------------------------------------------------------------
__global__ __launch_bounds__(256) void ret_out(const float* __restrict__ q,
                                               const float* __restrict__ k,
                                               const float* __restrict__ v,
                                               const float* __restrict__ P,
                                               float* __restrict__ out) {
  int bh = blockIdx.x, c = blockIdx.y;
  int b = bh >> 3, h = bh & 7;
  __shared__ float qt[CC][DH + 1];
  __shared__ float kt[CC][DH + 1];
  __shared__ float sc[CC][CC + 2];
  __shared__ float dp[CC + 1];
  int tid = threadIdx.x;
  size_t base = ((size_t)(b * TT + c * CC)) * DIM + h * DH;
#pragma unroll
  for (int l = 0; l < 16; ++l) {
    int e = tid + 256 * l;
    int j = e >> 6, d = e & 63;
    qt[j][d] = q[base + (size_t)j * DIM + d];
    kt[j][d] = k[base + (size_t)j * DIM + d];
  }
  if (tid <= CC) dp[tid] = __powf(DECAY, (float)tid);
  __syncthreads();
  int i = tid >> 2, j0 = (tid & 3) * 16;
  for (int jj = 0; jj < 16; ++jj) {
    int j = j0 + jj;
    float s = 0.f;
    if (j <= i) {
      for (int d = 0; d < DH; ++d) s = fmaf(qt[i][d], kt[j][d], s);
      s *= dp[i - j];
    }
    sc[i][j] = s;
  }
  __syncthreads();
#pragma unroll
  for (int l = 0; l < 16; ++l) {
    int e = tid + 256 * l;
    int j = e >> 6, d = e & 63;
    kt[j][d] = v[base + (size_t)j * DIM + d];
  }
  int e0 = j0;
  float acc[16];
#pragma unroll
  for (int u = 0; u < 16; ++u) acc[u] = 0.f;
  const float* Pg = P + ((size_t)(c * BHN + bh)) * 4096;
  for (int d = 0; d < DH; ++d) {
    float qd = qt[i][d];
#pragma unroll
    for (int u = 0; u < 16; ++u) acc[u] = fmaf(qd, Pg[d * 64 + e0 + u], acc[u]);
  }
  float di = dp[i + 1];
#pragma unroll
  for (int u = 0; u < 16; ++u) acc[u] *= di;
  __syncthreads();
  for (int j = 0; j < CC; ++j) {
    float s = sc[i][j];
#pragma unroll
    for (int u = 0; u < 16; ++u) acc[u] = fmaf(s, kt[j][e0 + u], acc[u]);
  }
  float* op = out + base;
#pragma unroll
  for (int u = 0; u < 16; ++u) op[(size_t)i * DIM + e0 + u] += acc[u];
}

// ---------------------------------------------------------------------------
extern "C" void kernel_launch(void* const* d_in, const int* in_sizes, int n_in,
                              void* d_out, int out_size, void* d_ws, size_t ws_size,
                              hipStream_t stream) {
  const float* q  = (const float*)d_in[0];
  const float* k  = (const float*)d_in[1];
  const float* v  = (const float*)d_in[2];
  const float* Wa = (const float*)d_in[3];
  const float* ba = (const float*)d_in[4];
  const float* Wb = (const float*)d_in[5];
  const float* bb = (const float*)d_in[6];
  const float* Wg = (const float*)d_in[7];
  const float* bg = (const float*)d_in[8];
  const float* Wo = (const float*)d_in[9];
  const float* bo = (const float*)d_in[10];
  float* out = (float*)d_out;
  float* ws = (float*)d_ws;

  const size_t NEL = (size_t)BB * TT * DIM;  // 4,194,304
  float* Abuf = ws;                          // fp32 a; KV aliases after scan
  float* Bbuf = ws + NEL;                    // fp32 b
  float* Gbuf = ws + 2 * NEL;                // fp32 g
  u16* qbf    = (u16*)(ws + 3 * NEL);        // bf16 q; hgbf aliases after gemm3
  u16* WtAll  = (u16*)(ws + 3 * NEL + NEL / 2);  // 4x 512x512 bf16 W^T
  float* SA   = ws + 3 * NEL + NEL / 2 + 524288 / 2;  // careful: WtAll = 1M u16 = 512K floats
  // recompute cleanly in float units:
  // qbf: NEL u16 = NEL/2 floats; WtAll: 4*512*512 = 1048576 u16 = 524288 floats
  SA = ws + 3 * NEL + NEL / 2 + 524288;
  float* SB = SA + NSC * 2048;
  float* CY = SB + NSC * 2048;
  u16* hgbf = qbf;      // alias: qbf dead after gemm3
  float* KV = Abuf;     // alias: Abuf dead after scan_apply

  cvt_bf16<<<(int)(NEL / 4 / 256), 256, 0, stream>>>(q, qbf);
  wtrans<<<dim3(16, 16, 4), 256, 0, stream>>>(Wa, Wb, Wg, Wo, WtAll);

  // fused q @ {Wa|Wb|Wg}: N = 1536, act on groups 0 and 2
  gemm_bt<<<dim3(12, 64), 256, 0, stream>>>(qbf, WtAll, ba, bb, bg,
                                            Abuf, Bbuf, Gbuf, 0b101);

  scan_part<<<dim3(NSC, 8), 256, 0, stream>>>(Abuf, Bbuf, SA, SB);
  scan_carry<<<8, 256, 0, stream>>>(SA, SB, CY);
  scan_apply<<<dim3(NSC, 8), 256, 0, stream>>>(Abuf, Bbuf, Gbuf, CY, hgbf);

  // m_out = (h*g) @ Wo + bo -> out
  gemm_bt<<<dim3(4, 64), 256, 0, stream>>>(hgbf, WtAll + 3 * DIM * DIM,
                                           bo, bo, bo, out, out, out, 0);

  ret_kv<<<dim3(BHN, NC), 256, 0, stream>>>(k, v, KV);
  ret_scan<<<(BHN * 4096) / 256, 256, 0, stream>>>(KV);
  ret_out<<<dim3(BHN, NC), 256, 0, stream>>>(q, k, v, KV, out);
}

// Round 3
// 237.661 us; speedup vs baseline: 2.4725x; 1.3655x over previous
//
#include <hip/hip_runtime.h>
#include <hip/hip_bf16.h>

typedef unsigned short u16;

// Problem constants
#define BB 4
#define TT 2048
#define DIM 512
#define NH 8
#define DH 64
#define DECAY 0.9f

// Retention chunking
#define CC 64
#define NC 32
#define BHN 32

// Scan chunking
#define CHS 128
#define NSC 16

// GEMM tiling
#define TM 128
#define TN 128
#define BK 64

// ret_out LDS row stride (u16): 64 + 8 pad; 144 B rows keep 16B alignment,
// fragment b128 reads land 2-way max (free)
#define SS 72

typedef __attribute__((ext_vector_type(8))) short bf16x8;
typedef __attribute__((ext_vector_type(4))) float f32x4;

__device__ __forceinline__ u16 f2bfu(float f) {
  union { float f; unsigned int u; } c; c.f = f;
  unsigned int u = c.u + 0x7FFFu + ((c.u >> 16) & 1u);  // RNE
  return (u16)(u >> 16);
}
__device__ __forceinline__ float bf2f(u16 u) {
  union { unsigned int u; float f; } c; c.u = ((unsigned int)u) << 16;
  return c.f;
}

__device__ __forceinline__ void gl_lds16(const void* g, void* l) {
  __builtin_amdgcn_global_load_lds(
      (const __attribute__((address_space(1))) void*)g,
      (__attribute__((address_space(3))) void*)(unsigned int)(unsigned long long)l,
      16, 0, 0);
}

// ---------------------------------------------------------------------------
// cvt: fp32 -> bf16 (4 elems/thread)
// ---------------------------------------------------------------------------
__global__ void cvt_bf16(const float* __restrict__ x, u16* __restrict__ y) {
  int i = blockIdx.x * 256 + threadIdx.x;
  float4 f = ((const float4*)x)[i];
  ushort4 u;
  u.x = f2bfu(f.x); u.y = f2bfu(f.y); u.z = f2bfu(f.z); u.w = f2bfu(f.w);
  ((ushort4*)y)[i] = u;
}

// ---------------------------------------------------------------------------
// weight transpose + convert: Wt[m][n][k] = bf16(W_m[k][n])
// ---------------------------------------------------------------------------
__global__ void wtrans(const float* __restrict__ W0, const float* __restrict__ W1,
                       const float* __restrict__ W2, const float* __restrict__ W3,
                       u16* __restrict__ Wt) {
  __shared__ float t[32][33];
  int m = blockIdx.z;
  const float* W = (m == 0) ? W0 : (m == 1) ? W1 : (m == 2) ? W2 : W3;
  int n0 = blockIdx.x * 32, k0 = blockIdx.y * 32;
  int tx = threadIdx.x & 31, ty = threadIdx.x >> 5;
#pragma unroll
  for (int r = 0; r < 32; r += 8)
    t[ty + r][tx] = W[(size_t)(k0 + ty + r) * DIM + n0 + tx];
  __syncthreads();
  u16* o = Wt + (size_t)m * DIM * DIM;
#pragma unroll
  for (int r = 0; r < 32; r += 8)
    o[(size_t)(n0 + ty + r) * DIM + k0 + tx] = f2bfu(t[tx][ty + r]);
}

// ---------------------------------------------------------------------------
// MFMA GEMM (m97 structure): C = act(A @ Bt^T + bias), 128x128 tile
// ---------------------------------------------------------------------------
__global__ __launch_bounds__(256) void gemm_bt(
    const u16* __restrict__ A, const u16* __restrict__ Bt,
    const float* __restrict__ b0, const float* __restrict__ b1,
    const float* __restrict__ b2,
    float* __restrict__ C0, float* __restrict__ C1, float* __restrict__ C2,
    int act_mask) {
  __shared__ __align__(16) u16 As[TM * BK];
  __shared__ __align__(16) u16 Bs[TN * BK];
  int tid = threadIdx.x;
  int wave = tid >> 6, lane = tid & 63;
  int nTile = blockIdx.x, mTile = blockIdx.y;
  int group = (nTile * TN) >> 9;
  const float* bias = (group == 0) ? b0 : (group == 1) ? b1 : b2;
  float* C = (group == 0) ? C0 : (group == 1) ? C1 : C2;
  int act = (act_mask >> group) & 1;

  int wm = (wave >> 1) * 64, wn = (wave & 1) * 64;
  int rowA = lane & 15, khalf = lane >> 4;

  f32x4 acc[4][4];
#pragma unroll
  for (int i = 0; i < 4; ++i)
#pragma unroll
    for (int j = 0; j < 4; ++j) acc[i][j] = (f32x4){0.f, 0.f, 0.f, 0.f};

  const u16* Abase = A + (size_t)mTile * TM * 512;
  const u16* Bbase = Bt + (size_t)nTile * TN * 512;

  for (int kk = 0; kk < 512; kk += BK) {
#pragma unroll
    for (int i = 0; i < 4; ++i) {
      int o = (wave * 4 + i) * 64 + lane;
      int row = o >> 3, gk = (o & 7) ^ (row & 7);
      gl_lds16(Abase + (size_t)row * 512 + kk + gk * 8, &As[o * 8]);
    }
#pragma unroll
    for (int i = 0; i < 4; ++i) {
      int o = (wave * 4 + i) * 64 + lane;
      int row = o >> 3, gk = (o & 7) ^ (row & 7);
      gl_lds16(Bbase + (size_t)row * 512 + kk + gk * 8, &Bs[o * 8]);
    }
    __syncthreads();
#pragma unroll
    for (int k0 = 0; k0 < 2; ++k0) {
      bf16x8 af[4], bfr[4];
#pragma unroll
      for (int mi = 0; mi < 4; ++mi) {
        int rr = wm + mi * 16 + rowA;
        int gk = k0 * 4 + khalf;
        int o = rr * 8 + (gk ^ (rr & 7));
        af[mi] = *(const bf16x8*)&As[o * 8];
      }
#pragma unroll
      for (int ni = 0; ni < 4; ++ni) {
        int rr = wn + ni * 16 + rowA;
        int gk = k0 * 4 + khalf;
        int o = rr * 8 + (gk ^ (rr & 7));
        bfr[ni] = *(const bf16x8*)&Bs[o * 8];
      }
#pragma unroll
      for (int mi = 0; mi < 4; ++mi)
#pragma unroll
        for (int ni = 0; ni < 4; ++ni)
          acc[mi][ni] = __builtin_amdgcn_mfma_f32_16x16x32_bf16(
              af[mi], bfr[ni], acc[mi][ni], 0, 0, 0);
    }
    __syncthreads();
  }
  int cloc = lane & 15, rq = (lane >> 4) * 4;
#pragma unroll
  for (int mi = 0; mi < 4; ++mi) {
#pragma unroll
    for (int r = 0; r < 4; ++r) {
      int m = mTile * TM + wm + mi * 16 + rq + r;
#pragma unroll
      for (int ni = 0; ni < 4; ++ni) {
        int n = (nTile * TN + wn + ni * 16 + cloc) & 511;
        float vv = acc[mi][ni][r] + bias[n];
        if (act) vv = 1.0f / (1.0f + __expf(-vv));
        C[(size_t)m * 512 + n] = vv;
      }
    }
  }
}

// ---------------------------------------------------------------------------
// 3-phase chunk-parallel linear scan
// ---------------------------------------------------------------------------
__global__ void scan_part(const float* __restrict__ a, const float* __restrict__ b,
                          float* __restrict__ SA, float* __restrict__ SB) {
  int ci = blockIdx.x;
  int ch = blockIdx.y * 256 + threadIdx.x;
  int bb = ch >> 9, d = ch & 511;
  size_t base = ((size_t)bb * TT + ci * CHS) * DIM + d;
  float h = 0.f, pA = 1.f;
  for (int t = 0; t < CHS; ++t) {
    float av = a[base + (size_t)t * DIM];
    float bv = b[base + (size_t)t * DIM];
    h = fmaf(av, h, bv);
    pA *= av;
  }
  SA[ci * 2048 + ch] = pA;
  SB[ci * 2048 + ch] = h;
}

__global__ void scan_carry(const float* __restrict__ SA, const float* __restrict__ SB,
                           float* __restrict__ CY) {
  int ch = blockIdx.x * 256 + threadIdx.x;
  float carry = 0.f;
  for (int ci = 0; ci < NSC; ++ci) {
    CY[ci * 2048 + ch] = carry;
    carry = fmaf(SA[ci * 2048 + ch], carry, SB[ci * 2048 + ch]);
  }
}

__global__ void scan_apply(const float* __restrict__ a, const float* __restrict__ b,
                           const float* __restrict__ g, const float* __restrict__ CY,
                           u16* __restrict__ hg) {
  int ci = blockIdx.x;
  int ch = blockIdx.y * 256 + threadIdx.x;
  int bb = ch >> 9, d = ch & 511;
  size_t base = ((size_t)bb * TT + ci * CHS) * DIM + d;
  float h = CY[ci * 2048 + ch];
  for (int t = 0; t < CHS; ++t) {
    size_t idx = base + (size_t)t * DIM;
    h = fmaf(a[idx], h, b[idx]);
    hg[idx] = f2bfu(h * g[idx]);
  }
}

// ---------------------------------------------------------------------------
// Retention phase 1: per-chunk KV summary, TRANSPOSED state:
// KVT[c][bh][e][d] = sum_j decay^{CC-1-j} V[j][e] K[j][d]
// ---------------------------------------------------------------------------
__global__ __launch_bounds__(256) void ret_kv(const float* __restrict__ k,
                                              const float* __restrict__ v,
                                              float* __restrict__ KVT) {
  int bh = blockIdx.x, c = blockIdx.y;
  int b = bh >> 3, h = bh & 7;
  __shared__ float kt[CC][DH + 1];
  __shared__ float vt[CC][DH + 1];
  __shared__ float dp[CC];
  int tid = threadIdx.x;
  size_t base = ((size_t)(b * TT + c * CC)) * DIM + h * DH;
#pragma unroll
  for (int l = 0; l < 16; ++l) {
    int e = tid + 256 * l;
    int j = e >> 6, d = e & 63;
    kt[j][d] = k[base + (size_t)j * DIM + d];
    vt[j][d] = v[base + (size_t)j * DIM + d];
  }
  if (tid < CC) dp[tid] = __powf(DECAY, (float)(CC - 1 - tid));
  __syncthreads();
  int e = tid >> 2, d0 = (tid & 3) * 16;
  float acc[16];
#pragma unroll
  for (int u = 0; u < 16; ++u) acc[u] = 0.f;
  for (int j = 0; j < CC; ++j) {
    float vd = vt[j][e] * dp[j];
#pragma unroll
    for (int u = 0; u < 16; ++u) acc[u] = fmaf(vd, kt[j][d0 + u], acc[u]);
  }
  float* o = KVT + ((size_t)(c * BHN + bh)) * 4096 + e * 64 + d0;
#pragma unroll
  for (int u = 0; u < 16; ++u) o[u] = acc[u];
}

// ---------------------------------------------------------------------------
// Retention phase 2: exclusive chunk scan; emits bf16 P^T[e][d] per chunk
// ---------------------------------------------------------------------------
__global__ void ret_scan(const float* __restrict__ KVT, u16* __restrict__ Ptb) {
  int gid = blockIdx.x * 256 + threadIdx.x;
  int bh = gid >> 12, ed = gid & 4095;
  float carry = 0.f;
  const float dC = __powf(DECAY, (float)CC);
  for (int c = 0; c < NC; ++c) {
    size_t idx = ((size_t)(c * BHN + bh)) * 4096 + ed;
    Ptb[idx] = f2bfu(carry);
    carry = fmaf(dC, carry, KVT[idx]);
  }
}

// ---------------------------------------------------------------------------
// Retention phase 3 (MFMA): per (bh, chunk):
//   S = Q K^T (64x64, K=64); S~ = decay-mask(S) -> bf16 LDS
//   Q <- diag(decay^{i+1}) Q (in place, bf16)
//   O = [S~ | Q] @ [V^T ; P^T]  (K=128), out += O
// ---------------------------------------------------------------------------
__global__ __launch_bounds__(256) void ret_out(
    const float* __restrict__ qg, const float* __restrict__ kg,
    const float* __restrict__ vg, const u16* __restrict__ Ptb,
    float* __restrict__ out) {
  __shared__ __align__(16) u16 Qs[64 * SS];
  __shared__ __align__(16) u16 Ks[64 * SS];  // becomes V^T after S-phase
  __shared__ __align__(16) u16 Sa[64 * SS];
  __shared__ __align__(16) u16 Ps[64 * SS];
  __shared__ float dp[66];
  int bh = blockIdx.x, c = blockIdx.y;
  int b = bh >> 3, h = bh & 7;
  int tid = threadIdx.x;
  int wave = tid >> 6, lane = tid & 63;
  size_t base = ((size_t)(b * TT + c * CC)) * DIM + h * DH;
  if (tid < 66) dp[tid] = __powf(DECAY, (float)tid);
  int row = tid >> 2, part = tid & 3;
  // stage Q, K: fp32 global -> bf16 LDS row-major, 16 elems/thread
  {
    const float4* qs = (const float4*)(qg + base + (size_t)row * DIM + part * 16);
    const float4* ks = (const float4*)(kg + base + (size_t)row * DIM + part * 16);
    u16 tq[16], tk[16];
#pragma unroll
    for (int u4 = 0; u4 < 4; ++u4) {
      float4 fq = qs[u4], fk = ks[u4];
      tq[u4 * 4 + 0] = f2bfu(fq.x); tq[u4 * 4 + 1] = f2bfu(fq.y);
      tq[u4 * 4 + 2] = f2bfu(fq.z); tq[u4 * 4 + 3] = f2bfu(fq.w);
      tk[u4 * 4 + 0] = f2bfu(fk.x); tk[u4 * 4 + 1] = f2bfu(fk.y);
      tk[u4 * 4 + 2] = f2bfu(fk.z); tk[u4 * 4 + 3] = f2bfu(fk.w);
    }
    *(uint4*)&Qs[row * SS + part * 16] = *(uint4*)&tq[0];
    *(uint4*)&Qs[row * SS + part * 16 + 8] = *(uint4*)&tq[8];
    *(uint4*)&Ks[row * SS + part * 16] = *(uint4*)&tk[0];
    *(uint4*)&Ks[row * SS + part * 16 + 8] = *(uint4*)&tk[8];
  }
  __syncthreads();

  int wm = (wave >> 1) * 32, wn = (wave & 1) * 32;
  int rowA = lane & 15, khalf = lane >> 4;

  // --- S = Q K^T ---
  f32x4 accS[2][2];
#pragma unroll
  for (int i = 0; i < 2; ++i)
#pragma unroll
    for (int j = 0; j < 2; ++j) accS[i][j] = (f32x4){0.f, 0.f, 0.f, 0.f};
#pragma unroll
  for (int k0 = 0; k0 < 2; ++k0) {
    int g = k0 * 4 + khalf;
    bf16x8 af[2], bfv[2];
#pragma unroll
    for (int mi = 0; mi < 2; ++mi)
      af[mi] = *(const bf16x8*)&Qs[(wm + mi * 16 + rowA) * SS + g * 8];
#pragma unroll
    for (int ni = 0; ni < 2; ++ni)
      bfv[ni] = *(const bf16x8*)&Ks[(wn + ni * 16 + rowA) * SS + g * 8];
#pragma unroll
    for (int mi = 0; mi < 2; ++mi)
#pragma unroll
      for (int ni = 0; ni < 2; ++ni)
        accS[mi][ni] = __builtin_amdgcn_mfma_f32_16x16x32_bf16(
            af[mi], bfv[ni], accS[mi][ni], 0, 0, 0);
  }
  __syncthreads();  // all waves done reading Qs/Ks

  // --- masked S -> Sa (bf16, A-layout) ---
  int cloc = lane & 15, rq = (lane >> 4) * 4;
#pragma unroll
  for (int mi = 0; mi < 2; ++mi)
#pragma unroll
    for (int ni = 0; ni < 2; ++ni)
#pragma unroll
      for (int r = 0; r < 4; ++r) {
        int i = wm + mi * 16 + rq + r;
        int j = wn + ni * 16 + cloc;
        float sv = (j <= i) ? accS[mi][ni][r] * dp[i - j] : 0.f;
        Sa[i * SS + j] = f2bfu(sv);
      }
  // --- Q <- decay^{i+1} * Q (in place) ---
  {
    u16* qp = &Qs[row * SS + part * 16];
    float s = dp[row + 1];
#pragma unroll
    for (int u = 0; u < 16; ++u) qp[u] = f2bfu(bf2f(qp[u]) * s);
  }
  // --- V^T into Ks region ---
  {
    int j = row, e0 = part * 16;
    const float4* vs = (const float4*)(vg + base + (size_t)j * DIM + e0);
#pragma unroll
    for (int u4 = 0; u4 < 4; ++u4) {
      float4 fv = vs[u4];
      Ks[(e0 + u4 * 4 + 0) * SS + j] = f2bfu(fv.x);
      Ks[(e0 + u4 * 4 + 1) * SS + j] = f2bfu(fv.y);
      Ks[(e0 + u4 * 4 + 2) * SS + j] = f2bfu(fv.z);
      Ks[(e0 + u4 * 4 + 3) * SS + j] = f2bfu(fv.w);
    }
  }
  // --- P^T tile (already bf16 [e][d] in global) ---
  {
    const u16* Pg = Ptb + ((size_t)(c * BHN + bh)) * 4096;
    *(uint4*)&Ps[row * SS + part * 16] = *(const uint4*)&Pg[row * 64 + part * 16];
    *(uint4*)&Ps[row * SS + part * 16 + 8] = *(const uint4*)&Pg[row * 64 + part * 16 + 8];
  }
  __syncthreads();

  // --- O = [S~ | Q] @ [V^T ; P^T], K = 128 ---
  f32x4 accO[2][2];
#pragma unroll
  for (int i = 0; i < 2; ++i)
#pragma unroll
    for (int j = 0; j < 2; ++j) accO[i][j] = (f32x4){0.f, 0.f, 0.f, 0.f};
#pragma unroll
  for (int k0 = 0; k0 < 4; ++k0) {
    bf16x8 af[2], bfv[2];
#pragma unroll
    for (int mi = 0; mi < 2; ++mi) {
      int rr = wm + mi * 16 + rowA;
      if (k0 < 2)
        af[mi] = *(const bf16x8*)&Sa[rr * SS + (k0 * 4 + khalf) * 8];
      else
        af[mi] = *(const bf16x8*)&Qs[rr * SS + ((k0 - 2) * 4 + khalf) * 8];
    }
#pragma unroll
    for (int ni = 0; ni < 2; ++ni) {
      int rr = wn + ni * 16 + rowA;
      if (k0 < 2)
        bfv[ni] = *(const bf16x8*)&Ks[rr * SS + (k0 * 4 + khalf) * 8];
      else
        bfv[ni] = *(const bf16x8*)&Ps[rr * SS + ((k0 - 2) * 4 + khalf) * 8];
    }
#pragma unroll
    for (int mi = 0; mi < 2; ++mi)
#pragma unroll
      for (int ni = 0; ni < 2; ++ni)
        accO[mi][ni] = __builtin_amdgcn_mfma_f32_16x16x32_bf16(
            af[mi], bfv[ni], accO[mi][ni], 0, 0, 0);
  }
  // --- epilogue: out += O ---
#pragma unroll
  for (int mi = 0; mi < 2; ++mi)
#pragma unroll
    for (int r = 0; r < 4; ++r) {
      int i = wm + mi * 16 + rq + r;
#pragma unroll
      for (int ni = 0; ni < 2; ++ni) {
        int e = wn + ni * 16 + cloc;
        float* op = &out[base + (size_t)i * DIM + e];
        *op += accO[mi][ni][r];
      }
    }
}

// ---------------------------------------------------------------------------
extern "C" void kernel_launch(void* const* d_in, const int* in_sizes, int n_in,
                              void* d_out, int out_size, void* d_ws, size_t ws_size,
                              hipStream_t stream) {
  const float* q  = (const float*)d_in[0];
  const float* k  = (const float*)d_in[1];
  const float* v  = (const float*)d_in[2];
  const float* Wa = (const float*)d_in[3];
  const float* ba = (const float*)d_in[4];
  const float* Wb = (const float*)d_in[5];
  const float* bb = (const float*)d_in[6];
  const float* Wg = (const float*)d_in[7];
  const float* bg = (const float*)d_in[8];
  const float* Wo = (const float*)d_in[9];
  const float* bo = (const float*)d_in[10];
  float* out = (float*)d_out;
  float* ws = (float*)d_ws;

  const size_t NEL = (size_t)BB * TT * DIM;  // 4,194,304
  float* Abuf = ws;                          // a; KVT aliases after scan
  float* Bbuf = ws + NEL;                    // b
  float* Gbuf = ws + 2 * NEL;                // g; Ptb aliases after scan_apply
  u16* qbf    = (u16*)(ws + 3 * NEL);        // bf16 q; hgbf aliases after gemm1
  u16* WtAll  = (u16*)(ws + 3 * NEL + NEL / 2);
  float* SA   = ws + 3 * NEL + NEL / 2 + 524288;
  float* SB = SA + NSC * 2048;
  float* CY = SB + NSC * 2048;
  u16* hgbf = qbf;        // qbf dead after gemm1 (ret_out uses fp32 q)
  float* KVT = Abuf;      // Abuf dead after scan_apply
  u16* Ptb = (u16*)Gbuf;  // Gbuf dead after scan_apply

  cvt_bf16<<<(int)(NEL / 4 / 256), 256, 0, stream>>>(q, qbf);
  wtrans<<<dim3(16, 16, 4), 256, 0, stream>>>(Wa, Wb, Wg, Wo, WtAll);

  // fused q @ {Wa|Wb|Wg}: N = 1536, sigmoid on groups 0 and 2
  gemm_bt<<<dim3(12, 64), 256, 0, stream>>>(qbf, WtAll, ba, bb, bg,
                                            Abuf, Bbuf, Gbuf, 0b101);

  scan_part<<<dim3(NSC, 8), 256, 0, stream>>>(Abuf, Bbuf, SA, SB);
  scan_carry<<<8, 256, 0, stream>>>(SA, SB, CY);
  scan_apply<<<dim3(NSC, 8), 256, 0, stream>>>(Abuf, Bbuf, Gbuf, CY, hgbf);

  // m_out = (h*g) @ Wo + bo -> out
  gemm_bt<<<dim3(4, 64), 256, 0, stream>>>(hgbf, WtAll + 3 * DIM * DIM,
                                           bo, bo, bo, out, out, out, 0);

  ret_kv<<<dim3(BHN, NC), 256, 0, stream>>>(k, v, KVT);
  ret_scan<<<(BHN * 4096) / 256, 256, 0, stream>>>(KVT, Ptb);
  ret_out<<<dim3(BHN, NC), 256, 0, stream>>>(q, k, v, Ptb, out);
}